// Round 13
// baseline (160.184 us; speedup 1.0000x reference)
//
#include <hip/hip_runtime.h>
#include <math.h>

#define H 512
#define NN 8
#define NC 5

// ---------- math helpers (saturation-safe fast transcendentals) ----------
__device__ __forceinline__ float reluf(float x) { return x > 0.f ? x : 0.f; }

__device__ __forceinline__ float sigf(float x) {
    return 1.0f / (1.0f + __expf(-x));   // saturates cleanly, no NaN
}

__device__ __forceinline__ float tanh_fast(float x) {
    float ax = fabsf(x);
    float e = __expf(2.0f * ax);
    float t = 1.0f - 2.0f / (e + 1.0f);  // exp overflow -> exactly 1
    return copysignf(t, x);
}

// combine for one output column k; r1/r2 are the cell's [8][H] raw dots.
__device__ __forceinline__ float combine_fn(const float* __restrict__ r1,
                                            const float* __restrict__ r2,
                                            int k) {
    float t[8];
#pragma unroll
    for (int n = 0; n < 8; ++n)
        t[n] = reluf(r1[n * H + k]) + reluf(r2[n * H + k]);
    float m0 = reluf(t[0]) + sigf(t[3]);
    float m1 = sigf(t[1]) + tanh_fast(t[2]);
    float m2 = sigf(t[4]) * tanh_fast(t[5]);
    float m3 = sigf(t[6]) * reluf(t[7]);
    float m4 = sigf(m1) + tanh_fast(m2);
    float m5 = tanh_fast(m0) * tanh_fast(m3);
    float m6 = tanh_fast(m4) * tanh_fast(m5);
    return tanh_fast(m6);
}

struct Ptrs { const float* x[6]; };  // a,b,c,d,e,state_init

// raw layout: raw[cell][side][node][k]; side 0 = x@W1, side 1 = h@W2.
// cell stride = 2*NN*H = 8192 floats. No zeroing needed (direct stores).
// cnt: 16 ints, stride 16 (64B apart); zeroed by stage 0, used by stage 4.

// ---- stage kernel: cell i = 16 matvecs, atomic-free stores --------------
// grid = 16 matrices * 16 k-tiles(32 cols) = 256 blocks, 512 threads.
// Stage 4 additionally elects, per k-tile, the LAST of its 16 blocks
// (threadfence + atomicAdd; 16 atomics/counter only) to compute the final
// combine for its 32 columns and write d_out -- removes the k_final
// dispatch + gap.
__global__ __launch_bounds__(512) void k_stage(int cell, Ptrs P,
                                               const float* __restrict__ W1,
                                               const float* __restrict__ W2,
                                               float* __restrict__ raw,
                                               int* __restrict__ cnt,
                                               float* __restrict__ out) {
    const int t   = threadIdx.x;
    const int bid = blockIdx.x;
    const int j    = bid & 15;   // k-tile (32 cols)
    const int m    = bid >> 4;   // 0..15
    const int node = m & 7;
    const int side = m >> 3;     // 0 = W1/x side, 1 = W2/h side

    // stage 0 zeroes stage-4's last-block counters (visible via dispatch
    // boundaries on the stream)
    if (cell == 0 && bid < 16 && t == 0) cnt[bid * 16] = 0;

    const int cg = t & 7;        // float4 col-group within tile
    const int rg = t >> 3;       // row-group 0..63

    const float* Wsel = (side == 0 ? W1 : W2) +
                        (size_t)(cell * NN + node) * H * H;
    const float* Wp = Wsel + (size_t)rg * H + j * 32 + cg * 4;

    // prefetch all 8 W float4s (independent of h; latency hides under
    // the h/LDS phase below)
    float4 wv[8];
#pragma unroll
    for (int i = 0; i < 8; ++i)
        wv[i] = *(const float4*)(Wp + (size_t)(i * 64) * H);

    __shared__ float sh[H];
    if (side == 0) {
        sh[t] = P.x[cell][t];                    // x_i
    } else if (cell == 0) {
        sh[t] = P.x[5][t];                       // state_init
    } else {
        const float* pb = raw + (size_t)(cell - 1) * 2 * NN * H;
        sh[t] = combine_fn(pb, pb + NN * H, t);  // h_{i-1} (L2-hot)
    }
    __syncthreads();

    float4 acc = {0.f, 0.f, 0.f, 0.f};
#pragma unroll
    for (int i = 0; i < 8; ++i) {
        float s = sh[i * 64 + rg];               // 8-lane broadcast, no conflict
        acc.x = fmaf(s, wv[i].x, acc.x);
        acc.y = fmaf(s, wv[i].y, acc.y);
        acc.z = fmaf(s, wv[i].z, acc.z);
        acc.w = fmaf(s, wv[i].w, acc.w);
    }

    // tree-reduce over the 64 row-groups
    __shared__ float red[64][33];
    red[rg][cg * 4 + 0] = acc.x;
    red[rg][cg * 4 + 1] = acc.y;
    red[rg][cg * 4 + 2] = acc.z;
    red[rg][cg * 4 + 3] = acc.w;
    __syncthreads();
#pragma unroll
    for (int s = 32; s >= 1; s >>= 1) {
        if (rg < s) {
#pragma unroll
            for (int c2 = 0; c2 < 4; ++c2)
                red[rg][cg * 4 + c2] += red[rg + s][cg * 4 + c2];
        }
        __syncthreads();
    }
    if (rg == 0) {
        float* dst = raw + (size_t)cell * 2 * NN * H + (size_t)side * NN * H +
                     (size_t)node * H + j * 32 + cg * 4;
        dst[0] = red[0][cg * 4 + 0];
        dst[1] = red[0][cg * 4 + 1];
        dst[2] = red[0][cg * 4 + 2];
        dst[3] = red[0][cg * 4 + 3];
    }

    // ---- stage 4 only: last block per k-tile fuses the final combine ----
    if (cell == NC - 1) {
        __threadfence();                          // publish our stores
        __shared__ int winner;
        if (t == 0) winner = (atomicAdd(&cnt[j * 16], 1) == 15);
        __syncthreads();
        if (winner) {
            __threadfence();                      // order reads after atomic
            if (t < 32) {
                const float* base = raw + (size_t)(NC - 1) * 2 * NN * H;
                int k = j * 32 + t;
                out[k] = combine_fn(base, base + NN * H, k);
            }
        }
    }
}

extern "C" void kernel_launch(void* const* d_in, const int* in_sizes, int n_in,
                              void* d_out, int out_size, void* d_ws, size_t ws_size,
                              hipStream_t stream) {
    const float* W1 = (const float*)d_in[6];
    const float* W2 = (const float*)d_in[7];
    float* out = (float*)d_out;
    float* raw = (float*)d_ws;                    // [5][2][8][512] f32
    int*   cnt = (int*)((float*)d_ws + NC * 2 * NN * H);  // 16 ints, 64B stride

    Ptrs P;
    P.x[0] = (const float*)d_in[0];
    P.x[1] = (const float*)d_in[1];
    P.x[2] = (const float*)d_in[2];
    P.x[3] = (const float*)d_in[3];
    P.x[4] = (const float*)d_in[4];
    P.x[5] = (const float*)d_in[5];

    for (int cell = 0; cell < NC; ++cell)
        k_stage<<<dim3(256), dim3(512), 0, stream>>>(cell, P, W1, W2, raw,
                                                     cnt, out);
}

// Round 14
// 127.416 us; speedup vs baseline: 1.2572x; 1.2572x over previous
//
#include <hip/hip_runtime.h>
#include <math.h>

#define H 512
#define NN 8
#define NC 5

// ---------- math helpers (saturation-safe fast transcendentals) ----------
__device__ __forceinline__ float reluf(float x) { return x > 0.f ? x : 0.f; }

__device__ __forceinline__ float sigf(float x) {
    return 1.0f / (1.0f + __expf(-x));   // saturates cleanly, no NaN
}

__device__ __forceinline__ float tanh_fast(float x) {
    float ax = fabsf(x);
    float e = __expf(2.0f * ax);
    float t = 1.0f - 2.0f / (e + 1.0f);  // exp overflow -> exactly 1
    return copysignf(t, x);
}

// combine for one output column k; r1/r2 are the cell's [8][H] raw dots.
__device__ __forceinline__ float combine_fn(const float* __restrict__ r1,
                                            const float* __restrict__ r2,
                                            int k) {
    float t[8];
#pragma unroll
    for (int n = 0; n < 8; ++n)
        t[n] = reluf(r1[n * H + k]) + reluf(r2[n * H + k]);
    float m0 = reluf(t[0]) + sigf(t[3]);
    float m1 = sigf(t[1]) + tanh_fast(t[2]);
    float m2 = sigf(t[4]) * tanh_fast(t[5]);
    float m3 = sigf(t[6]) * reluf(t[7]);
    float m4 = sigf(m1) + tanh_fast(m2);
    float m5 = tanh_fast(m0) * tanh_fast(m3);
    float m6 = tanh_fast(m4) * tanh_fast(m5);
    return tanh_fast(m6);
}

struct Ptrs { const float* x[6]; };  // a,b,c,d,e,state_init

// raw layout: raw[cell][side][node][k]; side 0 = x@W1, side 1 = h@W2.
// cell stride = 2*NN*H = 8192 floats. No zeroing needed (direct stores).
// NO grid-wide sync / fences anywhere: R8 (grid.sync ~70us) and R13
// (last-block + threadfence ~40us) proved cross-XCD coherence ops are
// far more expensive than a dispatch boundary (~1.5us).

// ---- stage kernel: cell i = 16 matvecs, atomic-free ---------------------
// grid = 16 matrices * 16 k-tiles(32 cols) = 256 blocks, 512 threads.
// Each block reduces the FULL 512-row dot for its 32 columns:
//   prefetch 8x float4 of W (indep of h) -> compute h into LDS (W2 side
//   recomputes previous cell's combine; L2-hot) -> FMA ->
//   3-step __shfl_xor wave butterfly (rows within wave) ->
//   1KB LDS pass over the 8 waves -> 32 coalesced scalar stores.
__global__ __launch_bounds__(512) void k_stage(int cell, Ptrs P,
                                               const float* __restrict__ W1,
                                               const float* __restrict__ W2,
                                               float* __restrict__ raw) {
    const int t   = threadIdx.x;
    const int bid = blockIdx.x;
    const int j    = bid & 15;   // k-tile (32 cols)
    const int m    = bid >> 4;   // 0..15
    const int node = m & 7;
    const int side = m >> 3;     // 0 = W1/x side, 1 = W2/h side

    const int cg = t & 7;        // float4 col-group within tile
    const int rg = t >> 3;       // row-group 0..63
    const int w  = t >> 6;       // wave 0..7

    const float* Wsel = (side == 0 ? W1 : W2) +
                        (size_t)(cell * NN + node) * H * H;
    const float* Wp = Wsel + (size_t)rg * H + j * 32 + cg * 4;

    // prefetch all 8 W float4s (independent of h; latency hides under
    // the h/LDS phase below)
    float4 wv[8];
#pragma unroll
    for (int i = 0; i < 8; ++i)
        wv[i] = *(const float4*)(Wp + (size_t)(i * 64) * H);

    __shared__ float sh[H];
    if (side == 0) {
        sh[t] = P.x[cell][t];                    // x_i
    } else if (cell == 0) {
        sh[t] = P.x[5][t];                       // state_init
    } else {
        const float* pb = raw + (size_t)(cell - 1) * 2 * NN * H;
        sh[t] = combine_fn(pb, pb + NN * H, t);  // h_{i-1} (L2-hot)
    }
    __syncthreads();

    float4 acc = {0.f, 0.f, 0.f, 0.f};
#pragma unroll
    for (int i = 0; i < 8; ++i) {
        float s = sh[i * 64 + rg];               // 8-lane broadcast, no conflict
        acc.x = fmaf(s, wv[i].x, acc.x);
        acc.y = fmaf(s, wv[i].y, acc.y);
        acc.z = fmaf(s, wv[i].z, acc.z);
        acc.w = fmaf(s, wv[i].w, acc.w);
    }

    // wave butterfly over the 8 row-groups inside each wave (lane bits 3-5)
#pragma unroll
    for (int off = 8; off < 64; off <<= 1) {
        acc.x += __shfl_xor(acc.x, off);
        acc.y += __shfl_xor(acc.y, off);
        acc.z += __shfl_xor(acc.z, off);
        acc.w += __shfl_xor(acc.w, off);
    }

    // one LDS pass over the 8 waves
    __shared__ float red[8][32];
    if ((t & 56) == 0) {                         // one lane per (wave, cg)
        red[w][cg * 4 + 0] = acc.x;
        red[w][cg * 4 + 1] = acc.y;
        red[w][cg * 4 + 2] = acc.z;
        red[w][cg * 4 + 3] = acc.w;
    }
    __syncthreads();
    if (t < 32) {
        float s = 0.f;
#pragma unroll
        for (int ww = 0; ww < 8; ++ww) s += red[ww][t];
        raw[(size_t)cell * 2 * NN * H + (size_t)side * NN * H +
            (size_t)node * H + j * 32 + t] = s;
    }
}

// ---------- final combine -> out[512] ------------------------------------
__global__ __launch_bounds__(512) void k_final(const float* __restrict__ raw,
                                               float* __restrict__ out) {
    const int t = threadIdx.x;   // 1 block, 512 threads
    const float* base = raw + (size_t)(NC - 1) * 2 * NN * H;
    out[t] = combine_fn(base, base + NN * H, t);
}

extern "C" void kernel_launch(void* const* d_in, const int* in_sizes, int n_in,
                              void* d_out, int out_size, void* d_ws, size_t ws_size,
                              hipStream_t stream) {
    const float* W1 = (const float*)d_in[6];
    const float* W2 = (const float*)d_in[7];
    float* out = (float*)d_out;
    float* raw = (float*)d_ws;   // [5][2][8][512] f32, no zeroing needed

    Ptrs P;
    P.x[0] = (const float*)d_in[0];
    P.x[1] = (const float*)d_in[1];
    P.x[2] = (const float*)d_in[2];
    P.x[3] = (const float*)d_in[3];
    P.x[4] = (const float*)d_in[4];
    P.x[5] = (const float*)d_in[5];

    for (int cell = 0; cell < NC; ++cell)
        k_stage<<<dim3(256), dim3(512), 0, stream>>>(cell, P, W1, W2, raw);
    k_final<<<dim3(1), dim3(512), 0, stream>>>(raw, out);
}